// Round 3
// baseline (136.410 us; speedup 1.0000x reference)
//
#include <hip/hip_runtime.h>
#include <hip/hip_bf16.h>

namespace {

constexpr int T = 4, H = 128, W = 128, C = 256, HD = 8, K = 9, F = 32;
constexpr int M = T * H * W;  // 65536

typedef __attribute__((ext_vector_type(8))) short short8v;   // 8 bf16 (4 VGPR)
typedef __attribute__((ext_vector_type(4))) float f32x4;     // MFMA acc

__device__ __forceinline__ unsigned short f2bf(float f) {
  unsigned u = __float_as_uint(f);
  unsigned r = (u + 0x7fffu + ((u >> 16) & 1u)) >> 16;
  return (unsigned short)r;
}

__device__ __forceinline__ float bf2f(unsigned short u) {
  return __uint_as_float(((unsigned)u) << 16);
}

// ---------------------------------------------------------------------------
// Templated MFMA GEMM: Cout[m][n] = sum_k A[m][k] * B[n][k]  (+ bias[n])
// (unchanged from round 2 — both dispatches run near their HBM floors)
// ---------------------------------------------------------------------------
template <bool A_BF16, bool OUT_F32>
__global__ __launch_bounds__(256) void mfma_gemm(
    const void* __restrict__ Aptr, const float* __restrict__ Bw,
    void* __restrict__ Cptr, const float* __restrict__ bias) {
  __shared__ unsigned short As[128][40];
  __shared__ unsigned short Bs[128][40];
  const int m0 = blockIdx.x * 128;
  const int n0 = blockIdx.y * 128;
  const int t = threadIdx.x;
  const int lane = t & 63;
  const int wid = t >> 6;
  const int wm = wid >> 1, wn = wid & 1;
  const int fr = lane & 15;
  const int kg = lane >> 4;

  f32x4 acc[4][4];
#pragma unroll
  for (int ni = 0; ni < 4; ++ni) {
    float b = 0.f;
    if (OUT_F32) b = bias[n0 + wn * 64 + ni * 16 + fr];
#pragma unroll
    for (int mi = 0; mi < 4; ++mi) {
      acc[mi][ni][0] = b; acc[mi][ni][1] = b;
      acc[mi][ni][2] = b; acc[mi][ni][3] = b;
    }
  }

  for (int k0 = 0; k0 < C; k0 += 32) {
    __syncthreads();
    if (A_BF16) {
      const unsigned short* Ab = (const unsigned short*)Aptr;
#pragma unroll
      for (int i = 0; i < 2; ++i) {
        const int flat = t + i * 256;
        const int row = flat >> 2, kc = (flat & 3) * 8;
        *(short8v*)&As[row][kc] =
            *(const short8v*)(Ab + (size_t)(m0 + row) * C + k0 + kc);
      }
    } else {
      const float* Af = (const float*)Aptr;
#pragma unroll
      for (int i = 0; i < 4; ++i) {
        const int flat = t + i * 256;
        const int row = flat >> 3, kc = (flat & 7) * 4;
        const float4 v4 = *(const float4*)(Af + (size_t)(m0 + row) * C + k0 + kc);
        ushort4 o;
        o.x = f2bf(v4.x); o.y = f2bf(v4.y); o.z = f2bf(v4.z); o.w = f2bf(v4.w);
        *(ushort4*)&As[row][kc] = o;
      }
    }
#pragma unroll
    for (int i = 0; i < 4; ++i) {
      const int flat = t + i * 256;
      const int row = flat >> 3, kc = (flat & 7) * 4;
      const float4 v4 = *(const float4*)(Bw + (size_t)(n0 + row) * C + k0 + kc);
      ushort4 o;
      o.x = f2bf(v4.x); o.y = f2bf(v4.y); o.z = f2bf(v4.z); o.w = f2bf(v4.w);
      *(ushort4*)&Bs[row][kc] = o;
    }
    __syncthreads();
    short8v af[4], bfv[4];
#pragma unroll
    for (int mi = 0; mi < 4; ++mi)
      af[mi] = *(const short8v*)&As[wm * 64 + mi * 16 + fr][kg * 8];
#pragma unroll
    for (int ni = 0; ni < 4; ++ni)
      bfv[ni] = *(const short8v*)&Bs[wn * 64 + ni * 16 + fr][kg * 8];
#pragma unroll
    for (int mi = 0; mi < 4; ++mi)
#pragma unroll
      for (int ni = 0; ni < 4; ++ni)
        acc[mi][ni] = __builtin_amdgcn_mfma_f32_16x16x32_bf16(
            af[mi], bfv[ni], acc[mi][ni], 0, 0, 0);
  }

#pragma unroll
  for (int mi = 0; mi < 4; ++mi) {
#pragma unroll
    for (int ni = 0; ni < 4; ++ni) {
      const int gcol = n0 + wn * 64 + ni * 16 + fr;
#pragma unroll
      for (int r = 0; r < 4; ++r) {
        const int grow = m0 + wm * 64 + mi * 16 + kg * 4 + r;
        if (OUT_F32) {
          ((float*)Cptr)[(size_t)grow * C + gcol] = acc[mi][ni][r];
        } else {
          ((unsigned short*)Cptr)[(size_t)grow * C + gcol] = f2bf(acc[mi][ni][r]);
        }
      }
    }
  }
}

// ---------------------------------------------------------------------------
// Gather v2: spatially-tiled, XCD-chunk-swizzled, all heads co-resident.
// Block = 8x8 (h,w) tile at one t; 256 thr = fq(4) x head(8) x pw(8);
// 8 rounds over tile rows. Zero LDS.
// ---------------------------------------------------------------------------
__global__ __launch_bounds__(256) void gather_kernel(
    const unsigned short* __restrict__ v, const float* __restrict__ attn,
    const int* __restrict__ flows, unsigned short* __restrict__ agg) {
  // bijective XCD-chunk swizzle: nwg = 1024 = 8 XCDs * 128-block chunks.
  const int bid = (blockIdx.x & 7) * 128 + (blockIdx.x >> 3);
  // chunk-internal order: t fastest (4 t-planes of a tile consecutive),
  // then w-tile, then h-tile -> per-XCD v working set ~L2-sized.
  const int t = bid & 3;
  const int w0 = ((bid >> 2) & 15) * 8;
  const int h0 = (bid >> 6) * 8;
  const int tid = threadIdx.x;
  const int fq = tid & 3;
  const int head = (tid >> 2) & 7;
  const int pw = tid >> 5;  // 0..7
  const int foff = head * F + fq * 8;

#pragma unroll
  for (int r = 0; r < 8; ++r) {
    const int h = h0 + r;
    const int w = w0 + pw;
    const int m = (t << 14) | (h << 7) | w;
    const int pair = (head << 16) | m;
    const int base = pair * K;
    const int fbase = base * 3;

    int mm[K];
    float aw[K];
#pragma unroll
    for (int k = 0; k < K; ++k) {
      const int dt = __builtin_nontemporal_load(flows + fbase + k * 3 + 0);
      const int dh = __builtin_nontemporal_load(flows + fbase + k * 3 + 1);
      const int dw = __builtin_nontemporal_load(flows + fbase + k * 3 + 2);
      aw[k] = __builtin_nontemporal_load(attn + base + k);
      const int tt = min(max(t + dt, 0), T - 1);
      const int hh = min(max(h + dh, 0), H - 1);
      const int ww = min(max(w + dw, 0), W - 1);
      mm[k] = (tt << 14) | (hh << 7) | ww;
    }
    float facc[8] = {0.f, 0.f, 0.f, 0.f, 0.f, 0.f, 0.f, 0.f};
#pragma unroll
    for (int k = 0; k < K; ++k) {
      const short8v r8 = *(const short8v*)(v + (size_t)mm[k] * C + foff);
#pragma unroll
      for (int j = 0; j < 8; ++j)
        facc[j] += aw[k] * bf2f((unsigned short)r8[j]);
    }
    short8v o;
#pragma unroll
    for (int j = 0; j < 8; ++j) o[j] = (short)f2bf(facc[j]);
    *(short8v*)(agg + (size_t)m * C + foff) = o;
  }
}

// ---------------------------------------------------------------------------
// Fallback (ws too small): round-1 fused gather + fp32 proj GEMM. Proven.
// ---------------------------------------------------------------------------
__global__ __launch_bounds__(256) void agg_proj_kernel(
    const unsigned short* __restrict__ v, const float* __restrict__ attn,
    const int* __restrict__ flows, const float* __restrict__ proj_w,
    const float* __restrict__ proj_b, float* __restrict__ out) {
  __shared__ float Agg[32][C];
  __shared__ float Bs[32][C];
  const int bid = blockIdx.x;
  const int t = bid >> 9;
  const int h0 = ((bid >> 5) & 15) * 8;
  const int w0 = (bid & 31) * 4;
  const int tid = threadIdx.x;

  const int g = tid >> 3;
  const int f4 = (tid & 7) * 4;
#pragma unroll
  for (int r = 0; r < 8; ++r) {
    const int pi = r * 32 + g;
    const int pos = pi >> 3;
    const int head = pi & 7;
    const int h = h0 + (pos >> 2);
    const int w = w0 + (pos & 3);
    const int base = (((head * T + t) * H + h) * W + w) * K;
    const int fbase = base * 3;
    float4 acc = {0.f, 0.f, 0.f, 0.f};
#pragma unroll
    for (int k = 0; k < K; ++k) {
      const int dt = flows[fbase + k * 3 + 0];
      const int dh = flows[fbase + k * 3 + 1];
      const int dw = flows[fbase + k * 3 + 2];
      const float aw = attn[base + k];
      const int tt = min(max(t + dt, 0), T - 1);
      const int hh = min(max(h + dh, 0), H - 1);
      const int ww = min(max(w + dw, 0), W - 1);
      const int mm = (tt * H + hh) * W + ww;
      const ushort4 r4 = *(const ushort4*)(v + (size_t)mm * C + head * F + f4);
      acc.x += aw * bf2f(r4.x);
      acc.y += aw * bf2f(r4.y);
      acc.z += aw * bf2f(r4.z);
      acc.w += aw * bf2f(r4.w);
    }
    *(float4*)&Agg[pos][head * F + f4] = acc;
  }
  __syncthreads();

  const int tx = tid & 31;
  const int ty = tid >> 5;
  float acc2[4][8];
  {
    const float4 b0 = *(const float4*)(proj_b + tx * 8);
    const float4 b1 = *(const float4*)(proj_b + tx * 8 + 4);
#pragma unroll
    for (int i = 0; i < 4; ++i) {
      acc2[i][0] = b0.x; acc2[i][1] = b0.y; acc2[i][2] = b0.z; acc2[i][3] = b0.w;
      acc2[i][4] = b1.x; acc2[i][5] = b1.y; acc2[i][6] = b1.z; acc2[i][7] = b1.w;
    }
  }
  for (int k0 = 0; k0 < C; k0 += 32) {
#pragma unroll
    for (int i = 0; i < 8; ++i) {
      const float4 w4 = *(const float4*)(proj_w + (size_t)tid * C + k0 + i * 4);
      Bs[i * 4 + 0][tid] = w4.x;
      Bs[i * 4 + 1][tid] = w4.y;
      Bs[i * 4 + 2][tid] = w4.z;
      Bs[i * 4 + 3][tid] = w4.w;
    }
    __syncthreads();
#pragma unroll 4
    for (int kk = 0; kk < 32; ++kk) {
      const float4 bb0 = *(const float4*)&Bs[kk][tx * 8];
      const float4 bb1 = *(const float4*)&Bs[kk][tx * 8 + 4];
      float a[4];
#pragma unroll
      for (int i = 0; i < 4; ++i) a[i] = Agg[ty * 4 + i][k0 + kk];
#pragma unroll
      for (int i = 0; i < 4; ++i) {
        acc2[i][0] += a[i] * bb0.x;
        acc2[i][1] += a[i] * bb0.y;
        acc2[i][2] += a[i] * bb0.z;
        acc2[i][3] += a[i] * bb0.w;
        acc2[i][4] += a[i] * bb1.x;
        acc2[i][5] += a[i] * bb1.y;
        acc2[i][6] += a[i] * bb1.z;
        acc2[i][7] += a[i] * bb1.w;
      }
    }
    __syncthreads();
  }
#pragma unroll
  for (int i = 0; i < 4; ++i) {
    const int pos = ty * 4 + i;
    const int h = h0 + (pos >> 2);
    const int w = w0 + (pos & 3);
    const int m = (t * H + h) * W + w;
    float4 o0, o1;
    o0.x = acc2[i][0]; o0.y = acc2[i][1]; o0.z = acc2[i][2]; o0.w = acc2[i][3];
    o1.x = acc2[i][4]; o1.y = acc2[i][5]; o1.z = acc2[i][6]; o1.w = acc2[i][7];
    *(float4*)(out + (size_t)m * C + tx * 8) = o0;
    *(float4*)(out + (size_t)m * C + tx * 8 + 4) = o1;
  }
}

}  // namespace

extern "C" void kernel_launch(void* const* d_in, const int* in_sizes, int n_in,
                              void* d_out, int out_size, void* d_ws,
                              size_t ws_size, hipStream_t stream) {
  const float* x = (const float*)d_in[0];
  const float* attn = (const float*)d_in[1];
  const int* flows = (const int*)d_in[2];
  const float* v_w = (const float*)d_in[3];
  const float* proj_w = (const float*)d_in[4];
  const float* proj_b = (const float*)d_in[5];
  float* out = (float*)d_out;

  const size_t VBYTES = (size_t)M * C * 2;  // 32 MB bf16
  unsigned short* v = (unsigned short*)d_ws;

  dim3 g1(M / 128, C / 128);
  mfma_gemm<false, false><<<g1, 256, 0, stream>>>(x, v_w, v, nullptr);

  if (ws_size >= 2 * VBYTES) {
    unsigned short* agg = (unsigned short*)((char*)d_ws + VBYTES);
    gather_kernel<<<1024, 256, 0, stream>>>(v, attn, flows, agg);
    mfma_gemm<true, true><<<g1, 256, 0, stream>>>(agg, proj_w, out, proj_b);
  } else {
    const int nblk = T * (H / 8) * (W / 4);  // 2048
    agg_proj_kernel<<<nblk, 256, 0, stream>>>(v, attn, flows, proj_w, proj_b,
                                              out);
  }
}